// Round 9
// baseline (1380.989 us; speedup 1.0000x reference)
//
#include <hip/hip_runtime.h>
#include <cstdint>
#include <cstddef>

#define IN_C 128
#define HIDc 128
#define OUTc 64

using bf8 = __attribute__((ext_vector_type(8))) __bf16;
using f4  = __attribute__((ext_vector_type(4))) float;

// ---- bf16 helpers (RNE) ----
__device__ __forceinline__ unsigned short f2bf(float f) {
    unsigned int u = __float_as_uint(f);
    unsigned int r = (u + 0x7FFFu + ((u >> 16) & 1u)) >> 16;
    return (unsigned short)r;
}
__device__ __forceinline__ float bf2f(unsigned short h) {
    return __uint_as_float(((unsigned int)h) << 16);
}

// ---------------------------------------------------------------------------
// Graph build. Edge dtype detect (int64 vs int32 storage) is battle-tested.
// ---------------------------------------------------------------------------
__global__ void k_detect(const long long* ei, int n_nodes, int* flag) {
    int t = threadIdx.x;                    // blockDim = 64
    long long v = ei[t];
    int ok = (v >= 0 && v < (long long)n_nodes) ? 1 : 0;
    unsigned long long m = __ballot(ok);
    if (t == 0) *flag = (m == ~0ull) ? 1 : 0;
}

__global__ void k_cvt_hist(const void* ei, int twoE, int E, const int* flag,
                           int* __restrict__ out, int* __restrict__ deg, int n) {
    int i = blockIdx.x * blockDim.x + threadIdx.x;
    if (i >= twoE) return;
    int v = (*flag) ? (int)((const long long*)ei)[i] : ((const int*)ei)[i];
    out[i] = v;
    if (i >= E && (unsigned)v < (unsigned)n) atomicAdd(&deg[v], 1);
}

__global__ void k_dinv(const int* __restrict__ deg, float* __restrict__ dinv, int n) {
    int i = blockIdx.x * blockDim.x + threadIdx.x;
    if (i < n) dinv[i] = (deg[i] > 0) ? rsqrtf((float)deg[i]) : 0.0f;
}

__global__ void k_alloc(const int* __restrict__ deg, int* __restrict__ base,
                        int* __restrict__ cursor, int* __restrict__ counter, int n) {
    int i = blockIdx.x * blockDim.x + threadIdx.x;
    int lane = threadIdx.x & 63;
    int val = (i < n) ? deg[i] : 0;
    int scan = val;
    #pragma unroll
    for (int off = 1; off < 64; off <<= 1) {
        int t = __shfl_up(scan, off);
        if (lane >= off) scan += t;
    }
    int excl = scan - val;
    int total = __shfl(scan, 63);
    int wb = 0;
    if (lane == 0) wb = atomicAdd(counter, total);
    wb = __shfl(wb, 0);
    if (i < n) { base[i] = wb + excl; cursor[i] = wb + excl; }
}

__global__ void k_scatter(const int* __restrict__ eint, int E,
                          const float* __restrict__ dinv, int n,
                          int* __restrict__ cursor, int2* __restrict__ ew) {
    int e = blockIdx.x * blockDim.x + threadIdx.x;
    if (e >= E) return;
    int r = eint[e];
    int c = eint[E + e];
    if ((unsigned)r >= (unsigned)n || (unsigned)c >= (unsigned)n) return;
    int p = atomicAdd(&cursor[c], 1);
    int2 v; v.x = r; v.y = __float_as_int(dinv[r] * dinv[c]);
    ew[p] = v;
}

// ---------------------------------------------------------------------------
// Weight prep: W (nstack, K, N) fp32 -> Wt (nstack*N rows, K) bf16 (transposed).
// ---------------------------------------------------------------------------
__global__ void k_wprep(const float* __restrict__ W, unsigned short* __restrict__ Wt,
                        int K, int N) {
    int j = blockIdx.y;
    int idx = blockIdx.x * 256 + threadIdx.x;
    if (idx >= K * N) return;
    int k = idx / N, nn = idx - k * N;
    Wt[(size_t)j * N * K + (size_t)nn * K + k] = f2bf(W[(size_t)j * K * N + idx]);
}

__global__ void k_cast4(const float* __restrict__ x, unsigned short* __restrict__ y, int n4) {
    int i = blockIdx.x * 256 + threadIdx.x;
    if (i >= n4) return;
    float4 v = ((const float4*)x)[i];
    ushort4 o;
    o.x = f2bf(v.x); o.y = f2bf(v.y); o.z = f2bf(v.z); o.w = f2bf(v.w);
    ((ushort4*)y)[i] = o;
}

// ---------------------------------------------------------------------------
// LDS-FREE fused 3-way MFMA GEMM (fragment layout HW-verified, r6/r7).
// The bf16 memory layout matches the MFMA fragment layout exactly:
//   A-frag of lane = 16B contiguous run A[m][kk+q*8..+7]  (W-row-major piece)
//   B-frag of lane = 16B contiguous run Bt[n][kk+q*8..+7] (Bt is N x K)
// so both are single 16B global loads — no LDS staging, NO barriers in the
// K-loop. A-reuse across the 4 col-quarter waves hits L1; B (<=288 KB) is
// L1/L2-resident across all blocks. r8's k_mfma3 was barrier/latency-bound
// (MfmaUtil 5.6%, 5.4M LDS conflicts, 44 KB LDS) — this removes all three.
// AFFINE folds BN scale/shift + ReLU into the A fragment in-register.
// Block: 512 thr / 8 waves (2 row-halves x 4 col-quarters), tile 128 x NT.
// ---------------------------------------------------------------------------
template<int PW, bool AFFINE>
__global__ __launch_bounds__(512) void k_mfma3(
    const unsigned short* __restrict__ A0, const unsigned short* __restrict__ A1,
    const unsigned short* __restrict__ A2, int W, int M, int K,
    const unsigned short* __restrict__ Bt, const float* __restrict__ bias,
    const float* __restrict__ scale, const float* __restrict__ shift,
    unsigned short* __restrict__ C0, unsigned short* __restrict__ C1,
    unsigned short* __restrict__ C2)
{
    constexpr int NT = 3 * PW;          // 384 or 192
    constexpr int TN = NT / 64;         // 6 or 3
    int t = threadIdx.x;
    int wave = t >> 6, lane = t & 63;
    int m16 = lane & 15, q = lane >> 4;
    int rowHalf = wave & 1, colQ = wave >> 1;
    int row0 = blockIdx.x * 128;

    // Precompute per-lane row offsets (rows fixed across K-loop).
    size_t aoff[4];
    #pragma unroll
    for (int tm = 0; tm < 4; tm++) {
        int r = row0 + rowHalf * 64 + tm * 16 + m16;
        if (r >= M) r = M - 1;          // clamp (stores guarded)
        aoff[tm] = (size_t)r * W;
    }
    size_t boff[TN];
    #pragma unroll
    for (int tn = 0; tn < TN; tn++)
        boff[tn] = (size_t)(colQ * 16 * TN + tn * 16 + m16) * K;

    f4 acc[4][TN];
    #pragma unroll
    for (int i = 0; i < 4; i++)
        #pragma unroll
        for (int j = 0; j < TN; j++) acc[i][j] = (f4){0.f, 0.f, 0.f, 0.f};

    for (int kk = 0; kk < K; kk += 32) {
        int pi = kk / W;
        const unsigned short* Ap = (pi == 0) ? A0 : ((pi == 1) ? A1 : A2);
        int kl = kk - pi * W;           // piece-local k: A ONLY (B uses global kk)

        uint4 a4[4];
        #pragma unroll
        for (int tm = 0; tm < 4; tm++)
            a4[tm] = *(const uint4*)&Ap[aoff[tm] + kl + q * 8];

        if (AFFINE) {
            int ch0 = kk + q * 8;       // global channel of this lane's 8 elems
            float scv[8], shv[8];
            *(float4*)&scv[0] = *(const float4*)&scale[ch0];
            *(float4*)&scv[4] = *(const float4*)&scale[ch0 + 4];
            *(float4*)&shv[0] = *(const float4*)&shift[ch0];
            *(float4*)&shv[4] = *(const float4*)&shift[ch0 + 4];
            #pragma unroll
            for (int tm = 0; tm < 4; tm++) {
                unsigned int* w32 = (unsigned int*)&a4[tm];
                #pragma unroll
                for (int h = 0; h < 4; h++) {
                    unsigned int u = w32[h];
                    float lo = fmaxf(bf2f((unsigned short)(u & 0xffff)) * scv[2*h]     + shv[2*h],     0.f);
                    float hi = fmaxf(bf2f((unsigned short)(u >> 16))    * scv[2*h + 1] + shv[2*h + 1], 0.f);
                    w32[h] = (unsigned int)f2bf(lo) | ((unsigned int)f2bf(hi) << 16);
                }
            }
        }

        bf8 bfr[TN];
        #pragma unroll
        for (int tn = 0; tn < TN; tn++)
            bfr[tn] = *(const bf8*)&Bt[boff[tn] + kk + q * 8];

        #pragma unroll
        for (int tm = 0; tm < 4; tm++) {
            bf8 af = *(const bf8*)&a4[tm];
            #pragma unroll
            for (int tn = 0; tn < TN; tn++)
                acc[tm][tn] = __builtin_amdgcn_mfma_f32_16x16x32_bf16(
                    af, bfr[tn], acc[tm][tn], 0, 0, 0);
        }
    }

    #pragma unroll
    for (int tn = 0; tn < TN; tn++) {
        int col_base = colQ * 16 * TN + tn * 16;
        int j  = col_base / PW;
        int cc = col_base - j * PW + m16;
        unsigned short* Cj = (j == 0) ? C0 : ((j == 1) ? C1 : C2);
        float bi = bias[col_base + m16];
        #pragma unroll
        for (int tm = 0; tm < 4; tm++) {
            #pragma unroll
            for (int r = 0; r < 4; r++) {
                int row = row0 + rowHalf * 64 + tm * 16 + q * 4 + r;
                if (row >= M) continue;
                Cj[(size_t)row * PW + cc] = f2bf(acc[tm][tn][r] + bi);
            }
        }
    }
}

// ---------------------------------------------------------------------------
// LDS-free single-output MFMA GEMM (final projection). fp32 out.
// C(M x 64) = concat(A0,A1,A2)(M x K, piece width W) @ Bt^T + bias.
// 256 thr / 4 waves, each wave 32 rows x 64 cols.
// ---------------------------------------------------------------------------
__global__ __launch_bounds__(256) void k_mfma_fin(
    const unsigned short* __restrict__ A0, const unsigned short* __restrict__ A1,
    const unsigned short* __restrict__ A2, int W, int M, int K,
    const unsigned short* __restrict__ Bt, const float* __restrict__ bias,
    float* __restrict__ C, int ldc)
{
    constexpr int TM = 2, TN = 4;
    int t = threadIdx.x;
    int wave = t >> 6, lane = t & 63;
    int m16 = lane & 15, q = lane >> 4;
    int row0 = blockIdx.x * 128;
    int wr = wave * 32;

    size_t aoff[TM];
    #pragma unroll
    for (int tm = 0; tm < TM; tm++) {
        int r = row0 + wr + tm * 16 + m16;
        if (r >= M) r = M - 1;
        aoff[tm] = (size_t)r * W;
    }
    size_t boff[TN];
    #pragma unroll
    for (int tn = 0; tn < TN; tn++)
        boff[tn] = (size_t)(tn * 16 + m16) * K;

    f4 acc[TM][TN];
    #pragma unroll
    for (int i = 0; i < TM; i++)
        #pragma unroll
        for (int j = 0; j < TN; j++) acc[i][j] = (f4){0.f, 0.f, 0.f, 0.f};

    for (int kk = 0; kk < K; kk += 32) {
        int pi = kk / W;
        const unsigned short* Ap = (pi == 0) ? A0 : ((pi == 1) ? A1 : A2);
        int kl = kk - pi * W;

        bf8 af[TM], bfr[TN];
        #pragma unroll
        for (int tm = 0; tm < TM; tm++)
            af[tm] = *(const bf8*)&Ap[aoff[tm] + kl + q * 8];
        #pragma unroll
        for (int tn = 0; tn < TN; tn++)
            bfr[tn] = *(const bf8*)&Bt[boff[tn] + kk + q * 8];
        #pragma unroll
        for (int tm = 0; tm < TM; tm++)
            #pragma unroll
            for (int tn = 0; tn < TN; tn++)
                acc[tm][tn] = __builtin_amdgcn_mfma_f32_16x16x32_bf16(
                    af[tm], bfr[tn], acc[tm][tn], 0, 0, 0);
    }

    #pragma unroll
    for (int tm = 0; tm < TM; tm++) {
        #pragma unroll
        for (int tn = 0; tn < TN; tn++) {
            int col = tn * 16 + m16;
            float bi = bias[col];
            #pragma unroll
            for (int r = 0; r < 4; r++) {
                int row = row0 + wr + tm * 16 + q * 4 + r;
                if (row >= M) continue;
                C[(size_t)row * ldc + col] = acc[tm][tn][r] + bi;
            }
        }
    }
}

// ---------------------------------------------------------------------------
// SpMM (bf16 in/out, fp32 accumulate), packed edges, unroll-8.
// One wave per node. V=2 -> width 128, V=1 -> width 64.
// ---------------------------------------------------------------------------
template<int V, bool DUAL>
__global__ __launch_bounds__(256) void k_spmm(
    const unsigned short* __restrict__ S1, const unsigned short* __restrict__ S2,
    unsigned short* __restrict__ D1, unsigned short* __restrict__ D2, int width,
    const int* __restrict__ base, const int* __restrict__ deg,
    const int2* __restrict__ ew, int n)
{
    int node = blockIdx.x * 4 + threadIdx.y;
    if (node >= n) return;
    int tx = threadIdx.x;
    float a1[V], a2[V];
    #pragma unroll
    for (int v = 0; v < V; v++) { a1[v] = 0.f; if (DUAL) a2[v] = 0.f; }
    int b = base[node], end = b + deg[node];
    const unsigned short* P1 = S1 + tx * V;
    const unsigned short* P2 = DUAL ? (S2 + tx * V) : nullptr;
    constexpr int UN = 8;
    int e = b;
    for (; e + UN <= end; e += UN) {
        int2 ev[UN];
        #pragma unroll
        for (int u = 0; u < UN; u++) ev[u] = ew[e + u];
        unsigned int g1[UN], g2[UN];
        #pragma unroll
        for (int u = 0; u < UN; u++) {
            if (V == 2) g1[u] = *(const unsigned int*)(P1 + (size_t)ev[u].x * width);
            else        g1[u] = P1[(size_t)ev[u].x * width];
            if (DUAL) {
                if (V == 2) g2[u] = *(const unsigned int*)(P2 + (size_t)ev[u].x * width);
                else        g2[u] = P2[(size_t)ev[u].x * width];
            }
        }
        #pragma unroll
        for (int u = 0; u < UN; u++) {
            float we = __int_as_float(ev[u].y);
            if (V == 2) {
                a1[0] += we * bf2f((unsigned short)(g1[u] & 0xffff));
                a1[1] += we * bf2f((unsigned short)(g1[u] >> 16));
                if (DUAL) {
                    a2[0] += we * bf2f((unsigned short)(g2[u] & 0xffff));
                    a2[1] += we * bf2f((unsigned short)(g2[u] >> 16));
                }
            } else {
                a1[0] += we * bf2f((unsigned short)g1[u]);
                if (DUAL) a2[0] += we * bf2f((unsigned short)g2[u]);
            }
        }
    }
    for (; e < end; ++e) {
        int2 ev = ew[e];
        float we = __int_as_float(ev.y);
        if (V == 2) {
            unsigned int u1 = *(const unsigned int*)(P1 + (size_t)ev.x * width);
            a1[0] += we * bf2f((unsigned short)(u1 & 0xffff));
            a1[1] += we * bf2f((unsigned short)(u1 >> 16));
            if (DUAL) {
                unsigned int u2 = *(const unsigned int*)(P2 + (size_t)ev.x * width);
                a2[0] += we * bf2f((unsigned short)(u2 & 0xffff));
                a2[1] += we * bf2f((unsigned short)(u2 >> 16));
            }
        } else {
            a1[0] += we * bf2f(P1[(size_t)ev.x * width]);
            if (DUAL) a2[0] += we * bf2f(P2[(size_t)ev.x * width]);
        }
    }
    size_t o = (size_t)node * width + tx * V;
    if (V == 2) {
        ushort2 o1; o1.x = f2bf(a1[0]); o1.y = f2bf(a1[1]);
        *(ushort2*)&D1[o] = o1;
        if (DUAL) { ushort2 o2; o2.x = f2bf(a2[0]); o2.y = f2bf(a2[1]);
                    *(ushort2*)&D2[o] = o2; }
    } else {
        D1[o] = f2bf(a1[0]);
        if (DUAL) D2[o] = f2bf(a2[0]);
    }
}

// ---------------------------------------------------------------------------
// BatchNorm batch stats over concat of 3 bf16 N x 128 pieces (apply folded
// into the next GEMM's A fragments).
// ---------------------------------------------------------------------------
__global__ void k_bnstats(const unsigned short* __restrict__ p0,
                          const unsigned short* __restrict__ p1,
                          const unsigned short* __restrict__ p2,
                          float* __restrict__ sums, float* __restrict__ sumsq, int n)
{
    int c = threadIdx.x;
    int cc = c & 127;
    int pi = c >> 7;
    const unsigned short* src = (pi == 0) ? p0 : ((pi == 1) ? p1 : p2);
    float s = 0.f, s2 = 0.f;
    for (int r = blockIdx.x; r < n; r += gridDim.x) {
        float v = bf2f(src[(size_t)r * 128 + cc]);
        s += v; s2 += v * v;
    }
    atomicAdd(&sums[c], s);
    atomicAdd(&sumsq[c], s2);
}

__global__ void k_bnfin(const float* __restrict__ sums, const float* __restrict__ sumsq,
                        const float* __restrict__ g, const float* __restrict__ bb,
                        float* __restrict__ scale, float* __restrict__ shift,
                        int cat, float invn)
{
    int c = threadIdx.x;
    if (c >= cat) return;
    float mu  = sums[c] * invn;
    float var = sumsq[c] * invn - mu * mu;
    float sc  = g[c] * rsqrtf(var + 1e-5f);
    scale[c] = sc;
    shift[c] = bb[c] - mu * sc;
}

// Diagnostic: if workspace is too small, surface ws_size (MB) via d_out.
__global__ void k_diag(float* out, float val, int n) {
    int i = blockIdx.x * blockDim.x + threadIdx.x;
    if (i < n) out[i] = val;
}

// ---------------------------------------------------------------------------
extern "C" void kernel_launch(void* const* d_in, const int* in_sizes, int n_in,
                              void* d_out, int out_size, void* d_ws, size_t ws_size,
                              hipStream_t stream)
{
    const float* x    = (const float*)d_in[0];
    const void*  ei   = d_in[1];
    const float* W0   = (const float*)d_in[2];
    const float* b0   = (const float*)d_in[3];
    const float* W1   = (const float*)d_in[4];
    const float* b1   = (const float*)d_in[5];
    const float* W2   = (const float*)d_in[6];
    const float* b2   = (const float*)d_in[7];
    const float* bn0g = (const float*)d_in[8];
    const float* bn0b = (const float*)d_in[9];
    const float* bn1g = (const float*)d_in[10];
    const float* bn1b = (const float*)d_in[11];
    const float* fpW  = (const float*)d_in[12];
    const float* fpb  = (const float*)d_in[13];
    float* out = (float*)d_out;

    const int N    = in_sizes[0] / IN_C;
    const int twoE = in_sizes[1];
    const int E    = twoE / 2;

    // ---- workspace carve (~184 MB; budget 256 MiB) ----
    char* p = (char*)d_ws;
    auto alloc = [&](size_t bytes) -> char* {
        char* r = p; p += (bytes + 255) & ~(size_t)255; return r;
    };
    unsigned short* U[6];
    for (int i = 0; i < 6; i++) U[i] = (unsigned short*)alloc((size_t)N * 128 * 2);
    unsigned short* Wt0 = (unsigned short*)alloc((size_t)3 * 128 * 128 * 2);
    unsigned short* Wt1 = (unsigned short*)alloc((size_t)3 * 384 * 128 * 2);
    unsigned short* Wt2 = (unsigned short*)alloc((size_t)3 * 384 * 64 * 2);
    unsigned short* WtF = (unsigned short*)alloc((size_t)192 * 64 * 2);
    float* dinv  = (float*)alloc((size_t)N * 4);
    int2*  ew    = (int2*)alloc((size_t)E * 8);
    float* sums  = (float*)alloc(2 * 384 * 4);
    float* sumsq = sums + 384;
    float* scale = (float*)alloc(384 * 4);
    float* shift = (float*)alloc(384 * 4);
    int* deg     = (int*)alloc((size_t)N * 4);
    int* base    = (int*)alloc((size_t)N * 4);
    int* cursor  = (int*)alloc((size_t)N * 4);
    int* eint    = (int*)alloc((size_t)twoE * 4);
    int* counter = (int*)alloc(4);
    int* flag    = (int*)alloc(4);

    size_t required = (size_t)(p - (char*)d_ws);
    if (required > ws_size) {
        k_diag<<<(out_size + 255) / 256, 256, 0, stream>>>(
            out, (float)(ws_size >> 20), out_size);
        return;
    }

    const int T = 256;
    dim3 spmm_blk(64, 4);
    int  spmm_grid = (N + 3) / 4;
    int  gx128 = (N + 127) / 128;

    // ---- weight prep + input cast ----
    k_wprep<<<dim3((128 * 128 + 255) / 256, 3), T, 0, stream>>>(W0, Wt0, 128, 128);
    k_wprep<<<dim3((384 * 128 + 255) / 256, 3), T, 0, stream>>>(W1, Wt1, 384, 128);
    k_wprep<<<dim3((384 * 64  + 255) / 256, 3), T, 0, stream>>>(W2, Wt2, 384, 64);
    k_wprep<<<dim3((192 * 64  + 255) / 256, 1), T, 0, stream>>>(fpW, WtF, 192, 64);
    unsigned short* Xb = U[3];
    k_cast4<<<((N * 128 / 4) + 255) / 256, T, 0, stream>>>(x, Xb, N * 128 / 4);

    // ---- graph build ----
    hipMemsetAsync(deg, 0, (size_t)N * 4, stream);
    hipMemsetAsync(counter, 0, 4, stream);
    k_detect<<<1, 64, 0, stream>>>((const long long*)ei, N, flag);
    k_cvt_hist<<<(twoE + T - 1) / T, T, 0, stream>>>(ei, twoE, E, flag, eint, deg, N);
    k_dinv<<<(N + T - 1) / T, T, 0, stream>>>(deg, dinv, N);
    k_alloc<<<(N + T - 1) / T, T, 0, stream>>>(deg, base, cursor, counter, N);
    k_scatter<<<(E + T - 1) / T, T, 0, stream>>>(eint, E, dinv, N, cursor, ew);

    // ---- layer 0: Xb(=U3) -> G0:U0, G1:U1, G2:U2 (one fused GEMM) ----
    k_mfma3<128, false><<<gx128, 512, 0, stream>>>(Xb, Xb, Xb, 128, N, 128,
        Wt0, b0, nullptr, nullptr, U[0], U[1], U[2]);
    // H1 = A*G1 -> U4 ; T = A*G2 -> U5 ; H2 = A*T -> U3
    k_spmm<2, true ><<<spmm_grid, spmm_blk, 0, stream>>>(U[1], U[2], U[4], U[5], 128,
                                                         base, deg, ew, N);
    k_spmm<2, false><<<spmm_grid, spmm_blk, 0, stream>>>(U[5], nullptr, U[3], nullptr, 128,
                                                         base, deg, ew, N);
    hipMemsetAsync(sums, 0, 2 * 384 * 4, stream);
    k_bnstats<<<2048, 384, 0, stream>>>(U[0], U[4], U[3], sums, sumsq, N);
    k_bnfin<<<1, 384, 0, stream>>>(sums, sumsq, bn0g, bn0b, scale, shift, 384, 1.0f / N);
    // layer-0 raw output (U0, U4, U3); BN+ReLU folded into next GEMM A-frags.

    // ---- layer 1: affine(U0,U4,U3) -> G0:U1, G1:U2, G2:U5 ----
    k_mfma3<128, true><<<gx128, 512, 0, stream>>>(U[0], U[4], U[3], 128, N, 384,
        Wt1, b1, scale, shift, U[1], U[2], U[5]);
    // H1 = A*G1 -> U0 ; T = A*G2 -> U4 ; H2 = A*T -> U3
    k_spmm<2, true ><<<spmm_grid, spmm_blk, 0, stream>>>(U[2], U[5], U[0], U[4], 128,
                                                         base, deg, ew, N);
    k_spmm<2, false><<<spmm_grid, spmm_blk, 0, stream>>>(U[4], nullptr, U[3], nullptr, 128,
                                                         base, deg, ew, N);
    hipMemsetAsync(sums, 0, 2 * 384 * 4, stream);
    k_bnstats<<<2048, 384, 0, stream>>>(U[1], U[0], U[3], sums, sumsq, N);
    k_bnfin<<<1, 384, 0, stream>>>(sums, sumsq, bn1g, bn1b, scale, shift, 384, 1.0f / N);
    // layer-1 raw output (U1, U0, U3)

    // ---- layer 2: affine(U1,U0,U3) -> 64-wide pieces in halves of U2/U4/U5 ----
    unsigned short* V2a = U[2];
    unsigned short* V2b = U[2] + (size_t)N * 64;
    unsigned short* V4a = U[4];
    unsigned short* V4b = U[4] + (size_t)N * 64;
    unsigned short* V5a = U[5];
    unsigned short* V5b = U[5] + (size_t)N * 64;
    k_mfma3<64, true><<<gx128, 512, 0, stream>>>(U[1], U[0], U[3], 128, N, 384,
        Wt2, b2, scale, shift, V2a, V2b, V4a);
    // A*L1(V2b) -> V4b ; T = A*L2(V4a) -> V5a ; A*T -> V5b
    k_spmm<1, true ><<<spmm_grid, spmm_blk, 0, stream>>>(V2b, V4a, V4b, V5a, 64,
                                                         base, deg, ew, N);
    k_spmm<1, false><<<spmm_grid, spmm_blk, 0, stream>>>(V5a, nullptr, V5b, nullptr, 64,
                                                         base, deg, ew, N);

    // ---- final projection: out = concat(V2a, V4b, V5b)(N x 192) @ fpW + fpb ----
    k_mfma_fin<<<gx128, T, 0, stream>>>(V2a, V4b, V5b, 64, N, 192, WtF, fpb, out, 64);
}